// Round 5
// baseline (153.577 us; speedup 1.0000x reference)
//
#include <hip/hip_runtime.h>

#define NTHREADS 256

typedef __attribute__((ext_vector_type(8))) short bf16x8;
typedef __attribute__((ext_vector_type(4))) float f32x4;
typedef __attribute__((ext_vector_type(2))) unsigned uint2v;
typedef __attribute__((ext_vector_type(4))) unsigned uint4v;

constexpr int kB = 16, kS = 2048, kD = 128;
constexpr int QBLK = 64, KBLK = 64, NROUNDS = kS / KBLK;  // 32
constexpr int MSTRIDE = 68;
constexpr float kNegMax = -3.402823466e38f;
constexpr float kMClamp = -1e30f;   // running-max floor: guards all-masked subtiles

__device__ __forceinline__ unsigned cvt_pk(float lo, float hi) {
    unsigned r;
    asm("v_cvt_pk_bf16_f32 %0, %1, %2" : "=v"(r) : "v"(lo), "v"(hi));
    return r;
}

// K swizzle (R4-proven): reads have l15 in row low bits
#define SWZ(bytecol, row) ((bytecol) ^ (((row) & 7) << 4))
// VT swizzle (R4-proven): write rows +4, read rows +1
#define SWZV(bytecol, row) ((bytecol) ^ (((((row) & 7) ^ (((row) >> 2) & 7)) & 7) << 4))
// P swizzle: 16B-block XOR within 64B row (write b64 / read b128 consistent)
#define SWZP(bytecol, row) ((bytecol) ^ (((row) & 3) << 4))

__global__ __launch_bounds__(NTHREADS, 2)
void attn_fwd(const float* __restrict__ q, const float* __restrict__ k,
              const float* __restrict__ v, const int* __restrict__ mask,
              float* __restrict__ out)
{
    // LDS: K 16K | Vt 16K | P 8K (2K/wave) | mask 64x68
    __shared__ __align__(16) char smem[45312];
    char* K_lds  = smem;              // [64 kv][128 d] bf16, stride 256B, SWZ
    char* VT_lds = smem + 16384;      // [128 d][64 kv] bf16, stride 128B, SWZV
    char* P_lds  = smem + 32768;      // [4 w][2 qs][16 q][32 k] bf16, row 64B, SWZP
    unsigned char* M_lds = (unsigned char*)(smem + 40960);  // [64 q][68] bytes

    const int tid = threadIdx.x, lane = tid & 63, w = tid >> 6;
    const int l15 = lane & 15, lg = lane >> 4;
    const int h = w >> 1;   // q-half: rows qbase + h*32 .. +31
    const int p = w & 1;    // k-parity: k-local p*32 .. p*32+31 of each round

    // XCD-aware swizzle: contiguous q-tiles (whole batches) per XCD
    const int bid = (int)blockIdx.x;
    const int swz = (bid & 7) * 64 + (bid >> 3);
    const int b = swz >> 5;
    const int qbase = (swz & 31) * QBLK;

    // ---- hoist Q^T fragments (B-operand of swapped QK), pre-scaled ----
    const float scale = 0.08838834764831845f;
    bf16x8 qf[2][4];
    #pragma unroll
    for (int qs = 0; qs < 2; ++qs) {
        const float* qp = q + ((size_t)(b*kS + qbase + h*32 + qs*16 + l15)) * kD;
        #pragma unroll
        for (int kk = 0; kk < 4; ++kk) {
            float4 a = *(const float4*)(qp + kk*32 + lg*8);
            float4 c = *(const float4*)(qp + kk*32 + lg*8 + 4);
            uint4v pk = { cvt_pk(a.x*scale, a.y*scale), cvt_pk(a.z*scale, a.w*scale),
                          cvt_pk(c.x*scale, c.y*scale), cvt_pk(c.z*scale, c.w*scale) };
            qf[qs][kk] = __builtin_bit_cast(bf16x8, pk);
        }
    }

    // acc = O^T[d][q=l15] per qsub: d = dblk*16 + lg*4 + i
    f32x4 acc[2][8];
    #pragma unroll
    for (int qs = 0; qs < 2; ++qs)
        #pragma unroll
        for (int d = 0; d < 8; ++d) acc[qs][d] = f32x4{0.f,0.f,0.f,0.f};
    float m_r[2] = {kMClamp, kMClamp};
    float l_r[2] = {0.f, 0.f};

    const float* kbat = k + (size_t)b * kS * kD;
    const float* vbat = v + (size_t)b * kS * kD;
    const int*   mbat = mask + ((size_t)b * kS + qbase) * kS;

    char* Pw = P_lds + w * 2048;

    // ---- T14 prefetch registers ----
    float4 kreg[4][2];
    float4 vreg[2][4];
    int4   mreg[4];

    auto LOAD = [&](int kt0) {
        #pragma unroll
        for (int c = 0; c < 4; ++c) {
            int chunk = c * 256 + tid;
            int row = chunk >> 4, col8 = chunk & 15;
            const float4* ptr = (const float4*)(kbat + (size_t)(kt0 + row)*kD + col8*8);
            kreg[c][0] = ptr[0];
            kreg[c][1] = ptr[1];
        }
        #pragma unroll
        for (int it = 0; it < 2; ++it) {
            int blk = it * 256 + tid;
            int kg = blk >> 5, dg = blk & 31;
            #pragma unroll
            for (int r = 0; r < 4; ++r)
                vreg[it][r] = *(const float4*)(vbat + (size_t)(kt0 + kg*4 + r)*kD + dg*4);
        }
        #pragma unroll
        for (int c = 0; c < 4; ++c) {
            int idx = c * 256 + tid;
            int mrow = idx >> 4, mc4 = idx & 15;
            mreg[c] = *(const int4*)(mbat + (size_t)mrow*kS + kt0 + mc4*4);
        }
    };

    auto STORE = [&]() {
        #pragma unroll
        for (int c = 0; c < 4; ++c) {
            int chunk = c * 256 + tid;
            int row = chunk >> 4, col8 = chunk & 15;
            uint4v pk = { cvt_pk(kreg[c][0].x, kreg[c][0].y), cvt_pk(kreg[c][0].z, kreg[c][0].w),
                          cvt_pk(kreg[c][1].x, kreg[c][1].y), cvt_pk(kreg[c][1].z, kreg[c][1].w) };
            *(uint4v*)(K_lds + row*256 + SWZ(col8*16, row)) = pk;
        }
        #pragma unroll
        for (int it = 0; it < 2; ++it) {
            int blk = it * 256 + tid;
            int kg = blk >> 5, dg = blk & 31;
            #pragma unroll
            for (int jj = 0; jj < 4; ++jj) {
                int row = dg * 4 + jj;
                uint2v pk = { cvt_pk((&vreg[it][0].x)[jj], (&vreg[it][1].x)[jj]),
                              cvt_pk((&vreg[it][2].x)[jj], (&vreg[it][3].x)[jj]) };
                *(uint2v*)(VT_lds + row*128 + SWZV(kg*8, row)) = pk;
            }
        }
        #pragma unroll
        for (int c = 0; c < 4; ++c) {
            int idx = c * 256 + tid;
            int mrow = idx >> 4, mc4 = idx & 15;
            unsigned pk = (unsigned)(mreg[c].x != 0)
                        | ((unsigned)(mreg[c].y != 0) << 8)
                        | ((unsigned)(mreg[c].z != 0) << 16)
                        | ((unsigned)(mreg[c].w != 0) << 24);
            *(unsigned*)(M_lds + mrow*MSTRIDE + mc4*4) = pk;
        }
    };

    LOAD(0);

    for (int t = 0; t < NROUNDS; ++t) {
        __syncthreads();
        STORE();
        __syncthreads();
        if (t + 1 < NROUNDS) LOAD((t + 1) * KBLK);

        // ---- S^T = K · Q^T : z[qs][kt][i] = S[k = p*32+kt*16+lg*4+i][q = l15-row] ----
        f32x4 z[2][2];
        #pragma unroll
        for (int qs = 0; qs < 2; ++qs)
            #pragma unroll
            for (int kt = 0; kt < 2; ++kt) z[qs][kt] = f32x4{0.f,0.f,0.f,0.f};
        #pragma unroll
        for (int kt = 0; kt < 2; ++kt) {
            bf16x8 kf[4];
            int krow = p*32 + kt*16 + l15;
            #pragma unroll
            for (int kk = 0; kk < 4; ++kk)
                kf[kk] = *(const bf16x8*)(K_lds + krow*256 + SWZ(kk*64 + lg*16, krow));
            #pragma unroll
            for (int qs = 0; qs < 2; ++qs)
                #pragma unroll
                for (int kk = 0; kk < 4; ++kk)
                    z[qs][kt] = __builtin_amdgcn_mfma_f32_16x16x32_bf16(kf[kk], qf[qs][kk], z[qs][kt], 0, 0, 0);
        }

        // ---- mask + online softmax (in-lane over 8 + 2 shfl), write P ----
        #pragma unroll
        for (int qs = 0; qs < 2; ++qs) {
            int mrow = h*32 + qs*16 + l15;
            float mx = kNegMax;
            #pragma unroll
            for (int kt = 0; kt < 2; ++kt) {
                unsigned nib = *(const unsigned*)(M_lds + mrow*MSTRIDE + p*32 + kt*16 + lg*4);
                #pragma unroll
                for (int i = 0; i < 4; ++i) {
                    float sv = ((nib >> (8*i)) & 0xFFu) ? kNegMax : z[qs][kt][i];
                    z[qs][kt][i] = sv;
                    mx = fmaxf(mx, sv);
                }
            }
            mx = fmaxf(mx, __shfl_xor(mx, 16));
            mx = fmaxf(mx, __shfl_xor(mx, 32));
            float mnew = fmaxf(m_r[qs], mx);   // >= kMClamp always
            float corr = __expf(m_r[qs] - mnew);
            float rs = 0.f;
            float pe[2][4];
            #pragma unroll
            for (int kt = 0; kt < 2; ++kt)
                #pragma unroll
                for (int i = 0; i < 4; ++i) {
                    pe[kt][i] = __expf(z[qs][kt][i] - mnew);
                    rs += pe[kt][i];
                }
            rs += __shfl_xor(rs, 16);
            rs += __shfl_xor(rs, 32);
            m_r[qs] = mnew;
            l_r[qs] = l_r[qs] * corr + rs;
            #pragma unroll
            for (int d = 0; d < 8; ++d) acc[qs][d] *= corr;
            #pragma unroll
            for (int kt = 0; kt < 2; ++kt) {
                uint2v pk = { cvt_pk(pe[kt][0], pe[kt][1]), cvt_pk(pe[kt][2], pe[kt][3]) };
                *(uint2v*)(Pw + qs*1024 + l15*64 + SWZP(kt*32 + lg*8, l15)) = pk;
            }
        }

        // ---- O^T += V^T · P^T ----
        bf16x8 pf[2];
        #pragma unroll
        for (int qs = 0; qs < 2; ++qs)
            pf[qs] = *(const bf16x8*)(Pw + qs*1024 + l15*64 + SWZP(lg*16, l15));
        #pragma unroll
        for (int dh = 0; dh < 2; ++dh) {
            bf16x8 vf[4];
            #pragma unroll
            for (int d4 = 0; d4 < 4; ++d4) {
                int vrow = (dh*4 + d4)*16 + l15;
                vf[d4] = *(const bf16x8*)(VT_lds + vrow*128 + SWZV(p*64 + lg*16, vrow));
            }
            #pragma unroll
            for (int qs = 0; qs < 2; ++qs)
                #pragma unroll
                for (int d4 = 0; d4 < 4; ++d4)
                    acc[qs][dh*4+d4] = __builtin_amdgcn_mfma_f32_16x16x32_bf16(vf[d4], pf[qs], acc[qs][dh*4+d4], 0, 0, 0);
        }
    }

    // ---- merge k-parity pairs (w, w^1) via LDS, then store ----
    __syncthreads();
    float* X  = (float*)smem;            // 32KB: [pair][qs][dblk][lane] f32x4
    float* ML = (float*)(smem + 32768);  // [pair][qs][{m,l}][lane]
    const int pair = w >> 1;
    if (w & 1) {
        #pragma unroll
        for (int qs = 0; qs < 2; ++qs) {
            #pragma unroll
            for (int d = 0; d < 8; ++d)
                *(f32x4*)(X + (((pair*2 + qs)*8 + d)*64 + lane)*4) = acc[qs][d];
            ML[((pair*2 + qs)*2 + 0)*64 + lane] = m_r[qs];
            ML[((pair*2 + qs)*2 + 1)*64 + lane] = l_r[qs];
        }
    }
    __syncthreads();
    if (!(w & 1)) {
        #pragma unroll
        for (int qs = 0; qs < 2; ++qs) {
            float mO = ML[((pair*2 + qs)*2 + 0)*64 + lane];
            float lO = ML[((pair*2 + qs)*2 + 1)*64 + lane];
            float mS = fmaxf(m_r[qs], mO);
            float fE = __expf(m_r[qs] - mS);
            float fO = __expf(mO - mS);
            float inv = 1.0f / (l_r[qs]*fE + lO*fO);
            int qrow = qbase + h*32 + qs*16 + l15;
            float* op = out + (size_t)(b*kS + qrow)*kD;
            #pragma unroll
            for (int d = 0; d < 8; ++d) {
                f32x4 aO = *(const f32x4*)(X + (((pair*2 + qs)*8 + d)*64 + lane)*4);
                float4 r;
                r.x = (acc[qs][d][0]*fE + aO[0]*fO) * inv;
                r.y = (acc[qs][d][1]*fE + aO[1]*fO) * inv;
                r.z = (acc[qs][d][2]*fE + aO[2]*fO) * inv;
                r.w = (acc[qs][d][3]*fE + aO[3]*fO) * inv;
                *(float4*)(op + d*16 + lg*4) = r;
            }
        }
    }
}

extern "C" void kernel_launch(void* const* d_in, const int* in_sizes, int n_in,
                              void* d_out, int out_size, void* d_ws, size_t ws_size,
                              hipStream_t stream) {
    const float* q = (const float*)d_in[0];
    const float* k = (const float*)d_in[1];
    const float* v = (const float*)d_in[2];
    const int* mask = (const int*)d_in[3];
    float* out = (float*)d_out;
    dim3 grid(kB * (kS / QBLK));   // 512 blocks
    dim3 block(NTHREADS);
    attn_fwd<<<grid, block, 0, stream>>>(q, k, v, mask, out);
}

// Round 6
// 153.331 us; speedup vs baseline: 1.0016x; 1.0016x over previous
//
#include <hip/hip_runtime.h>

#define NTHREADS 256

typedef __attribute__((ext_vector_type(8))) short bf16x8;
typedef __attribute__((ext_vector_type(4))) float f32x4;
typedef __attribute__((ext_vector_type(2))) unsigned uint2v;
typedef __attribute__((ext_vector_type(4))) unsigned uint4v;

constexpr int kB = 16, kS = 2048, kD = 128;
constexpr int QBLK = 64, KBLK = 64, NROUNDS = kS / KBLK;  // 32
constexpr int MSTRIDE = 68;
constexpr float kNegMax = -3.402823466e38f;
constexpr float kMClamp = -1e30f;   // running-max floor: guards all-masked subtiles

__device__ __forceinline__ unsigned cvt_pk(float lo, float hi) {
    unsigned r;
    asm("v_cvt_pk_bf16_f32 %0, %1, %2" : "=v"(r) : "v"(lo), "v"(hi));
    return r;
}

// K swizzle (R4-proven): reads have l15 in row low bits
#define SWZ(bytecol, row) ((bytecol) ^ (((row) & 7) << 4))
// VT swizzle (R4-proven): write rows +4, read rows +1
#define SWZV(bytecol, row) ((bytecol) ^ (((((row) & 7) ^ (((row) >> 2) & 7)) & 7) << 4))
// P swizzle: 16B-block XOR within 64B row (write b64 / read b128 consistent)
#define SWZP(bytecol, row) ((bytecol) ^ (((row) & 3) << 4))

__global__ __launch_bounds__(NTHREADS, 2)
void attn_fwd(const float* __restrict__ q, const float* __restrict__ k,
              const float* __restrict__ v, const int* __restrict__ mask,
              float* __restrict__ out)
{
    // LDS: K 16K | Vt 16K | P 8K (2K/wave) | mask 64x68
    __shared__ __align__(16) char smem[45312];
    char* K_lds  = smem;              // [64 kv][128 d] bf16, stride 256B, SWZ
    char* VT_lds = smem + 16384;      // [128 d][64 kv] bf16, stride 128B, SWZV
    char* P_lds  = smem + 32768;      // [4 w][2 qs][16 q][32 k] bf16, row 64B, SWZP
    unsigned char* M_lds = (unsigned char*)(smem + 40960);  // [64 q][68] bytes

    const int tid = threadIdx.x, lane = tid & 63, w = tid >> 6;
    const int l15 = lane & 15, lg = lane >> 4;
    const int h = w >> 1;   // q-half: rows qbase + h*32 .. +31
    const int p = w & 1;    // k-parity: k-local p*32 .. p*32+31 of each round

    // XCD-aware swizzle: contiguous q-tiles (whole batches) per XCD
    const int bid = (int)blockIdx.x;
    const int swz = (bid & 7) * 64 + (bid >> 3);
    const int b = swz >> 5;
    const int qbase = (swz & 31) * QBLK;

    // ---- hoist Q^T fragments (B-operand of swapped QK), pre-scaled ----
    const float scale = 0.08838834764831845f;
    bf16x8 qf[2][4];
    #pragma unroll
    for (int qs = 0; qs < 2; ++qs) {
        const float* qp = q + ((size_t)(b*kS + qbase + h*32 + qs*16 + l15)) * kD;
        #pragma unroll
        for (int kk = 0; kk < 4; ++kk) {
            float4 a = *(const float4*)(qp + kk*32 + lg*8);
            float4 c = *(const float4*)(qp + kk*32 + lg*8 + 4);
            uint4v pk = { cvt_pk(a.x*scale, a.y*scale), cvt_pk(a.z*scale, a.w*scale),
                          cvt_pk(c.x*scale, c.y*scale), cvt_pk(c.z*scale, c.w*scale) };
            qf[qs][kk] = __builtin_bit_cast(bf16x8, pk);
        }
    }

    // acc = O^T[d][q=l15] per qsub: d = dblk*16 + lg*4 + i
    f32x4 acc[2][8];
    #pragma unroll
    for (int qs = 0; qs < 2; ++qs)
        #pragma unroll
        for (int d = 0; d < 8; ++d) acc[qs][d] = f32x4{0.f,0.f,0.f,0.f};
    float m_r[2] = {kMClamp, kMClamp};
    float l_r[2] = {0.f, 0.f};

    const float* kbat = k + (size_t)b * kS * kD;
    const float* vbat = v + (size_t)b * kS * kD;
    const int*   mbat = mask + ((size_t)b * kS + qbase) * kS;

    char* Pw = P_lds + w * 2048;

    // ---- T14 prefetch registers ----
    float4 kreg[4][2];
    float4 vreg[2][4];
    int4   mreg[4];

    auto LOAD = [&](int kt0) {
        #pragma unroll
        for (int c = 0; c < 4; ++c) {
            int chunk = c * 256 + tid;
            int row = chunk >> 4, col8 = chunk & 15;
            const float4* ptr = (const float4*)(kbat + (size_t)(kt0 + row)*kD + col8*8);
            kreg[c][0] = ptr[0];
            kreg[c][1] = ptr[1];
        }
        #pragma unroll
        for (int it = 0; it < 2; ++it) {
            int blk = it * 256 + tid;
            int kg = blk >> 5, dg = blk & 31;
            #pragma unroll
            for (int r = 0; r < 4; ++r)
                vreg[it][r] = *(const float4*)(vbat + (size_t)(kt0 + kg*4 + r)*kD + dg*4);
        }
        #pragma unroll
        for (int c = 0; c < 4; ++c) {
            int idx = c * 256 + tid;
            int mrow = idx >> 4, mc4 = idx & 15;
            mreg[c] = *(const int4*)(mbat + (size_t)mrow*kS + kt0 + mc4*4);
        }
    };

    auto STORE = [&]() {
        #pragma unroll
        for (int c = 0; c < 4; ++c) {
            int chunk = c * 256 + tid;
            int row = chunk >> 4, col8 = chunk & 15;
            uint4v pk = { cvt_pk(kreg[c][0].x, kreg[c][0].y), cvt_pk(kreg[c][0].z, kreg[c][0].w),
                          cvt_pk(kreg[c][1].x, kreg[c][1].y), cvt_pk(kreg[c][1].z, kreg[c][1].w) };
            *(uint4v*)(K_lds + row*256 + SWZ(col8*16, row)) = pk;
        }
        #pragma unroll
        for (int it = 0; it < 2; ++it) {
            int blk = it * 256 + tid;
            int kg = blk >> 5, dg = blk & 31;
            #pragma unroll
            for (int jj = 0; jj < 4; ++jj) {
                int row = dg * 4 + jj;
                uint2v pk = { cvt_pk((&vreg[it][0].x)[jj], (&vreg[it][1].x)[jj]),
                              cvt_pk((&vreg[it][2].x)[jj], (&vreg[it][3].x)[jj]) };
                *(uint2v*)(VT_lds + row*128 + SWZV(kg*8, row)) = pk;
            }
        }
        #pragma unroll
        for (int c = 0; c < 4; ++c) {
            int idx = c * 256 + tid;
            int mrow = idx >> 4, mc4 = idx & 15;
            unsigned pk = (unsigned)(mreg[c].x != 0)
                        | ((unsigned)(mreg[c].y != 0) << 8)
                        | ((unsigned)(mreg[c].z != 0) << 16)
                        | ((unsigned)(mreg[c].w != 0) << 24);
            *(unsigned*)(M_lds + mrow*MSTRIDE + mc4*4) = pk;
        }
    };

    LOAD(0);

    for (int t = 0; t < NROUNDS; ++t) {
        __syncthreads();
        STORE();
        __syncthreads();
        if (t + 1 < NROUNDS) LOAD((t + 1) * KBLK);

        // ---- S^T = K · Q^T : z[qs][kt][i] = S[k = p*32+kt*16+lg*4+i][q = l15-row] ----
        f32x4 z[2][2];
        #pragma unroll
        for (int qs = 0; qs < 2; ++qs)
            #pragma unroll
            for (int kt = 0; kt < 2; ++kt) z[qs][kt] = f32x4{0.f,0.f,0.f,0.f};
        #pragma unroll
        for (int kt = 0; kt < 2; ++kt) {
            bf16x8 kf[4];
            int krow = p*32 + kt*16 + l15;
            #pragma unroll
            for (int kk = 0; kk < 4; ++kk)
                kf[kk] = *(const bf16x8*)(K_lds + krow*256 + SWZ(kk*64 + lg*16, krow));
            #pragma unroll
            for (int qs = 0; qs < 2; ++qs)
                #pragma unroll
                for (int kk = 0; kk < 4; ++kk)
                    z[qs][kt] = __builtin_amdgcn_mfma_f32_16x16x32_bf16(kf[kk], qf[qs][kk], z[qs][kt], 0, 0, 0);
        }

        // ---- mask + online softmax (in-lane over 8 + 2 shfl), write P ----
        #pragma unroll
        for (int qs = 0; qs < 2; ++qs) {
            int mrow = h*32 + qs*16 + l15;
            float mx = kNegMax;
            #pragma unroll
            for (int kt = 0; kt < 2; ++kt) {
                unsigned nib = *(const unsigned*)(M_lds + mrow*MSTRIDE + p*32 + kt*16 + lg*4);
                #pragma unroll
                for (int i = 0; i < 4; ++i) {
                    float sv = ((nib >> (8*i)) & 0xFFu) ? kNegMax : z[qs][kt][i];
                    z[qs][kt][i] = sv;
                    mx = fmaxf(mx, sv);
                }
            }
            mx = fmaxf(mx, __shfl_xor(mx, 16));
            mx = fmaxf(mx, __shfl_xor(mx, 32));
            float mnew = fmaxf(m_r[qs], mx);   // >= kMClamp always
            float corr = __expf(m_r[qs] - mnew);
            float rs = 0.f;
            float pe[2][4];
            #pragma unroll
            for (int kt = 0; kt < 2; ++kt)
                #pragma unroll
                for (int i = 0; i < 4; ++i) {
                    pe[kt][i] = __expf(z[qs][kt][i] - mnew);
                    rs += pe[kt][i];
                }
            rs += __shfl_xor(rs, 16);
            rs += __shfl_xor(rs, 32);
            m_r[qs] = mnew;
            l_r[qs] = l_r[qs] * corr + rs;
            #pragma unroll
            for (int d = 0; d < 8; ++d) acc[qs][d] *= corr;
            #pragma unroll
            for (int kt = 0; kt < 2; ++kt) {
                uint2v pk = { cvt_pk(pe[kt][0], pe[kt][1]), cvt_pk(pe[kt][2], pe[kt][3]) };
                *(uint2v*)(Pw + qs*1024 + l15*64 + SWZP(kt*32 + lg*8, l15)) = pk;
            }
        }

        // ---- O^T += V^T · P^T ----
        bf16x8 pf[2];
        #pragma unroll
        for (int qs = 0; qs < 2; ++qs)
            pf[qs] = *(const bf16x8*)(Pw + qs*1024 + l15*64 + SWZP(lg*16, l15));
        #pragma unroll
        for (int dh = 0; dh < 2; ++dh) {
            bf16x8 vf[4];
            #pragma unroll
            for (int d4 = 0; d4 < 4; ++d4) {
                int vrow = (dh*4 + d4)*16 + l15;
                vf[d4] = *(const bf16x8*)(VT_lds + vrow*128 + SWZV(p*64 + lg*16, vrow));
            }
            #pragma unroll
            for (int qs = 0; qs < 2; ++qs)
                #pragma unroll
                for (int d4 = 0; d4 < 4; ++d4)
                    acc[qs][dh*4+d4] = __builtin_amdgcn_mfma_f32_16x16x32_bf16(vf[d4], pf[qs], acc[qs][dh*4+d4], 0, 0, 0);
        }
    }

    // ---- merge k-parity pairs (w, w^1) via LDS, then store ----
    __syncthreads();
    float* X  = (float*)smem;            // 32KB: [pair][qs][dblk][lane] f32x4
    float* ML = (float*)(smem + 32768);  // [pair][qs][{m,l}][lane]
    const int pair = w >> 1;
    if (w & 1) {
        #pragma unroll
        for (int qs = 0; qs < 2; ++qs) {
            #pragma unroll
            for (int d = 0; d < 8; ++d)
                *(f32x4*)(X + (((pair*2 + qs)*8 + d)*64 + lane)*4) = acc[qs][d];
            ML[((pair*2 + qs)*2 + 0)*64 + lane] = m_r[qs];
            ML[((pair*2 + qs)*2 + 1)*64 + lane] = l_r[qs];
        }
    }
    __syncthreads();
    if (!(w & 1)) {
        #pragma unroll
        for (int qs = 0; qs < 2; ++qs) {
            float mO = ML[((pair*2 + qs)*2 + 0)*64 + lane];
            float lO = ML[((pair*2 + qs)*2 + 1)*64 + lane];
            float mS = fmaxf(m_r[qs], mO);
            float fE = __expf(m_r[qs] - mS);
            float fO = __expf(mO - mS);
            float inv = 1.0f / (l_r[qs]*fE + lO*fO);
            int qrow = qbase + h*32 + qs*16 + l15;
            float* op = out + (size_t)(b*kS + qrow)*kD;
            #pragma unroll
            for (int d = 0; d < 8; ++d) {
                f32x4 aO = *(const f32x4*)(X + (((pair*2 + qs)*8 + d)*64 + lane)*4);
                float4 r;
                r.x = (acc[qs][d][0]*fE + aO[0]*fO) * inv;
                r.y = (acc[qs][d][1]*fE + aO[1]*fO) * inv;
                r.z = (acc[qs][d][2]*fE + aO[2]*fO) * inv;
                r.w = (acc[qs][d][3]*fE + aO[3]*fO) * inv;
                *(float4*)(op + d*16 + lg*4) = r;
            }
        }
    }
}

extern "C" void kernel_launch(void* const* d_in, const int* in_sizes, int n_in,
                              void* d_out, int out_size, void* d_ws, size_t ws_size,
                              hipStream_t stream) {
    const float* q = (const float*)d_in[0];
    const float* k = (const float*)d_in[1];
    const float* v = (const float*)d_in[2];
    const int* mask = (const int*)d_in[3];
    float* out = (float*)d_out;
    dim3 grid(kB * (kS / QBLK));   // 512 blocks
    dim3 block(NTHREADS);
    attn_fwd<<<grid, block, 0, stream>>>(q, k, v, mask, out);
}

// Round 7
// 115.728 us; speedup vs baseline: 1.3271x; 1.3249x over previous
//
#include <hip/hip_runtime.h>

#define NTHREADS 256

typedef __attribute__((ext_vector_type(8))) short bf16x8;
typedef __attribute__((ext_vector_type(4))) float f32x4;
typedef __attribute__((ext_vector_type(2))) unsigned uint2v;
typedef __attribute__((ext_vector_type(4))) unsigned uint4v;

constexpr int kB = 16, kS = 2048, kD = 128;
constexpr int QBLK = 64, KBLK = 64, NROUNDS = kS / KBLK;  // 32
constexpr int MSTRIDE = 68;
constexpr float kNegMax = -3.402823466e38f;
constexpr float kMClamp = -1e30f;   // running-max floor

__device__ __forceinline__ unsigned cvt_pk(float lo, float hi) {
    unsigned r;
    asm("v_cvt_pk_bf16_f32 %0, %1, %2" : "=v"(r) : "v"(lo), "v"(hi));
    return r;
}

// K swizzle (R4-proven): reads have l15 in row low bits
#define SWZ(bytecol, row) ((bytecol) ^ (((row) & 7) << 4))
// VT swizzle (R4-proven): write rows +4, read rows +1
#define SWZV(bytecol, row) ((bytecol) ^ (((((row) & 7) ^ (((row) >> 2) & 7)) & 7) << 4))
// P swizzle: 128B rows, key row&7 — slot-counted min-phase on b64 write + b128 read
#define SWZP(bytecol, row) ((bytecol) ^ (((row) & 7) << 4))

__global__ __launch_bounds__(NTHREADS, 2)
void attn_fwd(const float* __restrict__ q, const float* __restrict__ k,
              const float* __restrict__ v, const int* __restrict__ mask,
              float* __restrict__ out)
{
    // LDS: K 16K | Vt 16K | P 8K (2K/wave) | mask 64x68
    __shared__ __align__(16) char smem[45312];
    char* K_lds  = smem;              // [64 kv][128 d] bf16, stride 256B, SWZ
    char* VT_lds = smem + 16384;      // [128 d][64 kv] bf16, stride 128B, SWZV
    char* P_lds  = smem + 32768;      // [4 w][16 q][64 k] bf16, row 128B, SWZP
    unsigned char* M_lds = (unsigned char*)(smem + 40960);  // [64 q][68] bytes

    const int tid = threadIdx.x, lane = tid & 63, w = tid >> 6;
    const int l15 = lane & 15, lg = lane >> 4;

    // XCD-aware swizzle: contiguous q-tiles (whole batches) per XCD
    const int bid = (int)blockIdx.x;
    const int swz = (bid & 7) * 64 + (bid >> 3);
    const int b = swz >> 5;
    const int qbase = (swz & 31) * QBLK;

    // ---- hoist Q^T fragments (B-operand of swapped QK), pre-scaled ----
    const float scale = 0.08838834764831845f;
    bf16x8 qf[4];
    {
        const float* qp = q + ((size_t)(b*kS + qbase + w*16 + l15)) * kD;
        #pragma unroll
        for (int kk = 0; kk < 4; ++kk) {
            float4 a = *(const float4*)(qp + kk*32 + lg*8);
            float4 c = *(const float4*)(qp + kk*32 + lg*8 + 4);
            uint4v pk = { cvt_pk(a.x*scale, a.y*scale), cvt_pk(a.z*scale, a.w*scale),
                          cvt_pk(c.x*scale, c.y*scale), cvt_pk(c.z*scale, c.w*scale) };
            qf[kk] = __builtin_bit_cast(bf16x8, pk);
        }
    }

    // acc[dblk] = O^T[d = dblk*16 + lg*4 + i][q = l15]
    f32x4 acc[8];
    #pragma unroll
    for (int d = 0; d < 8; ++d) acc[d] = f32x4{0.f,0.f,0.f,0.f};
    float m_r = kMClamp, l_r = 0.f;

    const float* kbat = k + (size_t)b * kS * kD;
    const float* vbat = v + (size_t)b * kS * kD;
    const int*   mbat = mask + ((size_t)b * kS + qbase) * kS;

    char* Pw = P_lds + w * 2048;

    // ---- T14 prefetch registers (same budget as R4, which fit at 128) ----
    float4 kreg[4][2];
    float4 vreg[2][4];
    int4   mreg[4];

    auto LOAD = [&](int kt0) {
        #pragma unroll
        for (int c = 0; c < 4; ++c) {
            int chunk = c * 256 + tid;
            int row = chunk >> 4, col8 = chunk & 15;
            const float4* ptr = (const float4*)(kbat + (size_t)(kt0 + row)*kD + col8*8);
            kreg[c][0] = ptr[0];
            kreg[c][1] = ptr[1];
        }
        #pragma unroll
        for (int it = 0; it < 2; ++it) {
            int blk = it * 256 + tid;
            int kg = blk >> 5, dg = blk & 31;
            #pragma unroll
            for (int r = 0; r < 4; ++r)
                vreg[it][r] = *(const float4*)(vbat + (size_t)(kt0 + kg*4 + r)*kD + dg*4);
        }
        #pragma unroll
        for (int c = 0; c < 4; ++c) {
            int idx = c * 256 + tid;
            int mrow = idx >> 4, mc4 = idx & 15;
            mreg[c] = *(const int4*)(mbat + (size_t)mrow*kS + kt0 + mc4*4);
        }
    };

    auto STORE = [&]() {
        #pragma unroll
        for (int c = 0; c < 4; ++c) {
            int chunk = c * 256 + tid;
            int row = chunk >> 4, col8 = chunk & 15;
            uint4v pk = { cvt_pk(kreg[c][0].x, kreg[c][0].y), cvt_pk(kreg[c][0].z, kreg[c][0].w),
                          cvt_pk(kreg[c][1].x, kreg[c][1].y), cvt_pk(kreg[c][1].z, kreg[c][1].w) };
            *(uint4v*)(K_lds + row*256 + SWZ(col8*16, row)) = pk;
        }
        #pragma unroll
        for (int it = 0; it < 2; ++it) {
            int blk = it * 256 + tid;
            int kg = blk >> 5, dg = blk & 31;
            #pragma unroll
            for (int jj = 0; jj < 4; ++jj) {
                int row = dg * 4 + jj;
                uint2v pk = { cvt_pk((&vreg[it][0].x)[jj], (&vreg[it][1].x)[jj]),
                              cvt_pk((&vreg[it][2].x)[jj], (&vreg[it][3].x)[jj]) };
                *(uint2v*)(VT_lds + row*128 + SWZV(kg*8, row)) = pk;
            }
        }
        #pragma unroll
        for (int c = 0; c < 4; ++c) {
            int idx = c * 256 + tid;
            int mrow = idx >> 4, mc4 = idx & 15;
            unsigned pk = (unsigned)(mreg[c].x != 0)
                        | ((unsigned)(mreg[c].y != 0) << 8)
                        | ((unsigned)(mreg[c].z != 0) << 16)
                        | ((unsigned)(mreg[c].w != 0) << 24);
            *(unsigned*)(M_lds + mrow*MSTRIDE + mc4*4) = pk;
        }
    };

    LOAD(0);

    for (int t = 0; t < NROUNDS; ++t) {
        __syncthreads();
        STORE();
        __syncthreads();
        if (t + 1 < NROUNDS) LOAD((t + 1) * KBLK);

        // ---- S^T = K · Q^T : z[kt][i] = S[k=kt*16+lg*4+i][q=l15] ----
        // kf/qf reads identical to R4's proven patterns; only operand order swapped.
        f32x4 z[4];
        #pragma unroll
        for (int kt = 0; kt < 4; ++kt) {
            f32x4 zz = f32x4{0.f,0.f,0.f,0.f};
            int krow = kt*16 + l15;
            #pragma unroll
            for (int kk = 0; kk < 4; ++kk) {
                bf16x8 kf = *(const bf16x8*)(K_lds + krow*256 + SWZ(kk*64 + lg*16, krow));
                zz = __builtin_amdgcn_mfma_f32_16x16x32_bf16(kf, qf[kk], zz, 0, 0, 0);
            }
            z[kt] = zz;
        }

        // ---- mask + in-lane online softmax (one q-row per lane) ----
        const int mrowb = (w*16 + l15) * MSTRIDE;
        float mx = kNegMax;
        #pragma unroll
        for (int kt = 0; kt < 4; ++kt) {
            unsigned nib = *(const unsigned*)(M_lds + mrowb + kt*16 + lg*4);
            #pragma unroll
            for (int i = 0; i < 4; ++i) {
                float sv = ((nib >> (8*i)) & 0xFFu) ? kNegMax : z[kt][i];
                z[kt][i] = sv;
                mx = fmaxf(mx, sv);
            }
        }
        mx = fmaxf(mx, __shfl_xor(mx, 16));
        mx = fmaxf(mx, __shfl_xor(mx, 32));
        float mnew = fmaxf(m_r, mx);
        float corr = __expf(m_r - mnew);
        float rs = 0.f;
        #pragma unroll
        for (int kt = 0; kt < 4; ++kt) {
            float p0 = __expf(z[kt][0] - mnew);
            float p1 = __expf(z[kt][1] - mnew);
            float p2 = __expf(z[kt][2] - mnew);
            float p3 = __expf(z[kt][3] - mnew);
            rs += (p0 + p1) + (p2 + p3);
            uint2v pk = { cvt_pk(p0, p1), cvt_pk(p2, p3) };
            *(uint2v*)(Pw + l15*128 + SWZP(kt*32 + lg*8, l15)) = pk;
        }
        rs += __shfl_xor(rs, 16);
        rs += __shfl_xor(rs, 32);
        m_r = mnew;
        l_r = l_r * corr + rs;
        #pragma unroll
        for (int d = 0; d < 8; ++d) acc[d] *= corr;

        // ---- O^T += V^T · P^T (intra-wave P handoff; no barrier needed) ----
        #pragma unroll
        for (int ks = 0; ks < 2; ++ks) {
            bf16x8 pf = *(const bf16x8*)(Pw + l15*128 + SWZP(ks*64 + lg*16, l15));
            #pragma unroll
            for (int dblk = 0; dblk < 8; ++dblk) {
                int vrow = dblk*16 + l15;
                bf16x8 vf = *(const bf16x8*)(VT_lds + vrow*128 + SWZV(ks*64 + lg*16, vrow));
                acc[dblk] = __builtin_amdgcn_mfma_f32_16x16x32_bf16(vf, pf, acc[dblk], 0, 0, 0);
            }
        }
    }

    // ---- epilogue: lane holds O[q = w*16+l15][d = dblk*16+lg*4+i] -> float4 stores ----
    float inv = 1.0f / l_r;
    float* op = out + ((size_t)(b*kS + qbase + w*16 + l15)) * kD;
    #pragma unroll
    for (int dblk = 0; dblk < 8; ++dblk) {
        float4 r;
        r.x = acc[dblk][0] * inv;
        r.y = acc[dblk][1] * inv;
        r.z = acc[dblk][2] * inv;
        r.w = acc[dblk][3] * inv;
        *(float4*)(op + dblk*16 + lg*4) = r;
    }
}

extern "C" void kernel_launch(void* const* d_in, const int* in_sizes, int n_in,
                              void* d_out, int out_size, void* d_ws, size_t ws_size,
                              hipStream_t stream) {
    const float* q = (const float*)d_in[0];
    const float* k = (const float*)d_in[1];
    const float* v = (const float*)d_in[2];
    const int* mask = (const int*)d_in[3];
    float* out = (float*)d_out;
    dim3 grid(kB * (kS / QBLK));   // 512 blocks
    dim3 block(NTHREADS);
    attn_fwd<<<grid, block, 0, stream>>>(q, k, v, mask, out);
}